// Round 3
// baseline (294.622 us; speedup 1.0000x reference)
//
#include <hip/hip_runtime.h>

#define HIDDEN 1024
#define SEQ 2048
#define NB 2

typedef _Float16 half8 __attribute__((ext_vector_type(8)));
typedef _Float16 half4 __attribute__((ext_vector_type(4)));
typedef float f32x4 __attribute__((ext_vector_type(4)));

// ---------------- cast x fp32 -> fp16 ----------------
__global__ __launch_bounds__(256) void cast_x(const float* __restrict__ x,
                                              _Float16* __restrict__ xh, int n) {
    int i = (blockIdx.x * 256 + threadIdx.x) * 4;
    if (i < n) {
        float4 v = *(const float4*)(x + i);
        half4 h;
        h[0] = (_Float16)v.x; h[1] = (_Float16)v.y;
        h[2] = (_Float16)v.z; h[3] = (_Float16)v.w;
        *(half4*)(xh + i) = h;
    }
}

// ---------------- cast + transpose Wq: wt[n][k] = Wq[k][n] ----------------
__global__ __launch_bounds__(256) void cast_wt(const float* __restrict__ w,
                                               _Float16* __restrict__ wt) {
    __shared__ float tile[32][33];
    int bx = blockIdx.x * 32, by = blockIdx.y * 32;
    int tx = threadIdx.x, ty = threadIdx.y;   // (32, 8)
    #pragma unroll
    for (int i = 0; i < 32; i += 8)
        tile[ty + i][tx] = w[(by + ty + i) * HIDDEN + bx + tx];
    __syncthreads();
    #pragma unroll
    for (int i = 0; i < 32; i += 8)
        wt[(bx + ty + i) * HIDDEN + by + tx] = (_Float16)tile[tx][ty + i];
}

// ---------------- projection GEMM: Q = x @ Wq + bq  (fp16 in/out, fp32 acc) ----------------
__global__ __launch_bounds__(256) void proj_gemm(const _Float16* __restrict__ A,
                                                 const _Float16* __restrict__ Bt,
                                                 const float* __restrict__ bias,
                                                 _Float16* __restrict__ Q) {
    __shared__ _Float16 As[128][72];
    __shared__ _Float16 Bs[128][72];
    const int m0 = blockIdx.x * 128;
    const int n0 = blockIdx.y * 128;
    const int tid = threadIdx.x;
    const int w = tid >> 6, l = tid & 63;
    const int wm = w >> 1, wn = w & 1;           // 2x2 waves, each 64x64
    const int lrow = l & 15, lk = (l >> 4) * 8;

    f32x4 acc[4][4] = {};

    for (int k0 = 0; k0 < HIDDEN; k0 += 64) {
        __syncthreads();
        #pragma unroll
        for (int i = 0; i < 4; ++i) {
            int id = tid + i * 256;
            int r = id >> 3, c = id & 7;
            *(half8*)&As[r][c * 8] = *(const half8*)&A[(size_t)(m0 + r) * HIDDEN + k0 + c * 8];
        }
        #pragma unroll
        for (int i = 0; i < 4; ++i) {
            int id = tid + i * 256;
            int r = id >> 3, c = id & 7;
            *(half8*)&Bs[r][c * 8] = *(const half8*)&Bt[(size_t)(n0 + r) * HIDDEN + k0 + c * 8];
        }
        __syncthreads();
        #pragma unroll
        for (int kk = 0; kk < 64; kk += 32) {
            half8 af[4], bf[4];
            #pragma unroll
            for (int m = 0; m < 4; ++m)
                af[m] = *(const half8*)&As[wm * 64 + m * 16 + lrow][kk + lk];
            #pragma unroll
            for (int n = 0; n < 4; ++n)
                bf[n] = *(const half8*)&Bs[wn * 64 + n * 16 + lrow][kk + lk];
            #pragma unroll
            for (int m = 0; m < 4; ++m)
                #pragma unroll
                for (int n = 0; n < 4; ++n)
                    acc[m][n] = __builtin_amdgcn_mfma_f32_16x16x32_f16(af[m], bf[n], acc[m][n], 0, 0, 0);
        }
    }
    const int lr4 = (l >> 4) * 4, lc = l & 15;
    #pragma unroll
    for (int n = 0; n < 4; ++n) {
        int gcol = n0 + wn * 64 + n * 16 + lc;
        float b = bias[gcol];
        #pragma unroll
        for (int m = 0; m < 4; ++m) {
            #pragma unroll
            for (int r = 0; r < 4; ++r) {
                int grow = m0 + wm * 64 + m * 16 + lr4 + r;
                Q[(size_t)grow * HIDDEN + gcol] = (_Float16)(acc[m][n][r] + b);
            }
        }
    }
}

// ---------------- fused scores + softmax, barrier-free ----------------
// K == Q (shared projection). One wave = 32 q-rows (2 q-frags). No LDS, no
// __syncthreads: K fragments come straight from global (L1/L2-resident,
// 256 KB per (b,h) slice). MFMA operands swapped (mfma(K,Q)) so the C layout
// is col=q (lane&15), row=k ((lane>>4)*4+reg) -> per-lane float4 stores over
// consecutive k. Pass A accumulates per-row sum(exp(e/8)); pass B recomputes
// and writes exp * rinv via non-temporal stores (don't thrash L2).
__global__ __launch_bounds__(256) void scores_softmax(const _Float16* __restrict__ Qh,
                                                      float* __restrict__ out) {
    const int h  = blockIdx.y;       // 0..15
    const int b  = blockIdx.z;       // 0..1
    const int tid = threadIdx.x;
    const int w = tid >> 6, l = tid & 63;
    const int lq = l & 15, lg = l >> 4;
    const int q0 = blockIdx.x * 128 + w * 32;
    const int hoff = h * 64;
    const _Float16* qb = Qh + (size_t)b * SEQ * HIDDEN;

    // Q fragments (B-operand): lane&15 = q-row, (lane>>4)*8 = d-offset
    const _Float16* qp = qb + (size_t)(q0 + lq) * HIDDEN + hoff + lg * 8;
    half8 aq[2][2];
    #pragma unroll
    for (int f = 0; f < 2; ++f)
        #pragma unroll
        for (int c = 0; c < 2; ++c)
            aq[f][c] = *(const half8*)(qp + (size_t)f * 16 * HIDDEN + c * 32);

    // K fragment base (A-operand): lane&15 = k-row, (lane>>4)*8 = d-offset
    const _Float16* kbase = qb + (size_t)lq * HIDDEN + hoff + lg * 8;

    float rsum[2] = {0.f, 0.f};

    // ---- Pass A: row sums of exp(e/8) ----
    for (int kt = 0; kt < 32; ++kt) {
        const _Float16* kp = kbase + (size_t)kt * 64 * HIDDEN;
        #pragma unroll
        for (int n = 0; n < 4; ++n) {
            half8 k0 = *(const half8*)(kp + (size_t)n * 16 * HIDDEN);
            half8 k1 = *(const half8*)(kp + (size_t)n * 16 * HIDDEN + 32);
            #pragma unroll
            for (int f = 0; f < 2; ++f) {
                f32x4 acc = {};
                acc = __builtin_amdgcn_mfma_f32_16x16x32_f16(k0, aq[f][0], acc, 0, 0, 0);
                acc = __builtin_amdgcn_mfma_f32_16x16x32_f16(k1, aq[f][1], acc, 0, 0, 0);
                rsum[f] += __expf(acc[0] * 0.125f) + __expf(acc[1] * 0.125f)
                         + __expf(acc[2] * 0.125f) + __expf(acc[3] * 0.125f);
            }
        }
    }
    #pragma unroll
    for (int f = 0; f < 2; ++f) {
        rsum[f] += __shfl_xor(rsum[f], 16);
        rsum[f] += __shfl_xor(rsum[f], 32);
    }
    const float rinv0 = 1.0f / rsum[0];
    const float rinv1 = 1.0f / rsum[1];

    // ---- Pass B: recompute + write ----
    const size_t outbase = (size_t)(b * 16 + h) * SEQ * SEQ;
    float* op = out + outbase + (size_t)(q0 + lq) * SEQ + lg * 4;
    for (int kt = 0; kt < 32; ++kt) {
        const _Float16* kp = kbase + (size_t)kt * 64 * HIDDEN;
        #pragma unroll
        for (int n = 0; n < 4; ++n) {
            half8 k0 = *(const half8*)(kp + (size_t)n * 16 * HIDDEN);
            half8 k1 = *(const half8*)(kp + (size_t)n * 16 * HIDDEN + 32);
            #pragma unroll
            for (int f = 0; f < 2; ++f) {
                f32x4 acc = {};
                acc = __builtin_amdgcn_mfma_f32_16x16x32_f16(k0, aq[f][0], acc, 0, 0, 0);
                acc = __builtin_amdgcn_mfma_f32_16x16x32_f16(k1, aq[f][1], acc, 0, 0, 0);
                float rinv = f ? rinv1 : rinv0;
                f32x4 v;
                v[0] = __expf(acc[0] * 0.125f) * rinv;
                v[1] = __expf(acc[1] * 0.125f) * rinv;
                v[2] = __expf(acc[2] * 0.125f) * rinv;
                v[3] = __expf(acc[3] * 0.125f) * rinv;
                __builtin_nontemporal_store(v,
                    (f32x4*)(op + (size_t)f * 16 * SEQ + kt * 64 + n * 16));
            }
        }
    }
}

extern "C" void kernel_launch(void* const* d_in, const int* in_sizes, int n_in,
                              void* d_out, int out_size, void* d_ws, size_t ws_size,
                              hipStream_t stream) {
    const float* x  = (const float*)d_in[0];   // [2,2048,1024]
    const float* Wq = (const float*)d_in[1];   // [1024,1024]
    const float* bq = (const float*)d_in[2];   // [1024]
    float* out = (float*)d_out;                // [2,16,2048,2048]

    _Float16* xh = (_Float16*)d_ws;                    // 8 MB
    _Float16* qh = xh + (size_t)4 * 1024 * 1024;       // 8 MB
    _Float16* wt = qh + (size_t)4 * 1024 * 1024;       // 2 MB

    const int nx = NB * SEQ * HIDDEN;  // 4194304
    cast_x<<<nx / (256 * 4), 256, 0, stream>>>(x, xh, nx);
    cast_wt<<<dim3(32, 32), dim3(32, 8), 0, stream>>>(Wq, wt);
    proj_gemm<<<dim3(NB * SEQ / 128, HIDDEN / 128), 256, 0, stream>>>(xh, wt, bq, qh);
    scores_softmax<<<dim3(SEQ / 128, 16, NB), 256, 0, stream>>>(qh, out);
}

// Round 4
// 180.687 us; speedup vs baseline: 1.6306x; 1.6306x over previous
//
#include <hip/hip_runtime.h>

#define HIDDEN 1024
#define SEQ 2048
#define NB 2
#define PSTRIDE 2052  // halfs per LDS score row: 2048 + 4 pad -> 4104 B (8B-aligned, bank-spread)

typedef _Float16 half8 __attribute__((ext_vector_type(8)));
typedef _Float16 half4 __attribute__((ext_vector_type(4)));
typedef float f32x4 __attribute__((ext_vector_type(4)));

// ---------------- cast x fp32 -> fp16 ----------------
__global__ __launch_bounds__(256) void cast_x(const float* __restrict__ x,
                                              _Float16* __restrict__ xh, int n) {
    int i = (blockIdx.x * 256 + threadIdx.x) * 4;
    if (i < n) {
        float4 v = *(const float4*)(x + i);
        half4 h;
        h[0] = (_Float16)v.x; h[1] = (_Float16)v.y;
        h[2] = (_Float16)v.z; h[3] = (_Float16)v.w;
        *(half4*)(xh + i) = h;
    }
}

// ---------------- cast + transpose Wq: wt[n][k] = Wq[k][n] ----------------
__global__ __launch_bounds__(256) void cast_wt(const float* __restrict__ w,
                                               _Float16* __restrict__ wt) {
    __shared__ float tile[32][33];
    int bx = blockIdx.x * 32, by = blockIdx.y * 32;
    int tx = threadIdx.x, ty = threadIdx.y;   // (32, 8)
    #pragma unroll
    for (int i = 0; i < 32; i += 8)
        tile[ty + i][tx] = w[(by + ty + i) * HIDDEN + bx + tx];
    __syncthreads();
    #pragma unroll
    for (int i = 0; i < 32; i += 8)
        wt[(bx + ty + i) * HIDDEN + by + tx] = (_Float16)tile[tx][ty + i];
}

// ---------------- projection GEMM: Q = x @ Wq + bq  (fp16 in/out, fp32 acc) ----------------
__global__ __launch_bounds__(256) void proj_gemm(const _Float16* __restrict__ A,
                                                 const _Float16* __restrict__ Bt,
                                                 const float* __restrict__ bias,
                                                 _Float16* __restrict__ Q) {
    __shared__ _Float16 As[128][72];
    __shared__ _Float16 Bs[128][72];
    const int m0 = blockIdx.x * 128;
    const int n0 = blockIdx.y * 128;
    const int tid = threadIdx.x;
    const int w = tid >> 6, l = tid & 63;
    const int wm = w >> 1, wn = w & 1;           // 2x2 waves, each 64x64
    const int lrow = l & 15, lk = (l >> 4) * 8;

    f32x4 acc[4][4] = {};

    for (int k0 = 0; k0 < HIDDEN; k0 += 64) {
        __syncthreads();
        #pragma unroll
        for (int i = 0; i < 4; ++i) {
            int id = tid + i * 256;
            int r = id >> 3, c = id & 7;
            *(half8*)&As[r][c * 8] = *(const half8*)&A[(size_t)(m0 + r) * HIDDEN + k0 + c * 8];
        }
        #pragma unroll
        for (int i = 0; i < 4; ++i) {
            int id = tid + i * 256;
            int r = id >> 3, c = id & 7;
            *(half8*)&Bs[r][c * 8] = *(const half8*)&Bt[(size_t)(n0 + r) * HIDDEN + k0 + c * 8];
        }
        __syncthreads();
        #pragma unroll
        for (int kk = 0; kk < 64; kk += 32) {
            half8 af[4], bf[4];
            #pragma unroll
            for (int m = 0; m < 4; ++m)
                af[m] = *(const half8*)&As[wm * 64 + m * 16 + lrow][kk + lk];
            #pragma unroll
            for (int n = 0; n < 4; ++n)
                bf[n] = *(const half8*)&Bs[wn * 64 + n * 16 + lrow][kk + lk];
            #pragma unroll
            for (int m = 0; m < 4; ++m)
                #pragma unroll
                for (int n = 0; n < 4; ++n)
                    acc[m][n] = __builtin_amdgcn_mfma_f32_16x16x32_f16(af[m], bf[n], acc[m][n], 0, 0, 0);
        }
    }
    const int lr4 = (l >> 4) * 4, lc = l & 15;
    #pragma unroll
    for (int n = 0; n < 4; ++n) {
        int gcol = n0 + wn * 64 + n * 16 + lc;
        float b = bias[gcol];
        #pragma unroll
        for (int m = 0; m < 4; ++m) {
            #pragma unroll
            for (int r = 0; r < 4; ++r) {
                int grow = m0 + wm * 64 + m * 16 + lr4 + r;
                Q[(size_t)grow * HIDDEN + gcol] = (_Float16)(acc[m][n][r] + b);
            }
        }
    }
}

// ---------------- fused scores + softmax: single matmul pass ----------------
// Block = 16 q-rows. p = exp(e/8 - 8) cached as fp16 in LDS (shift cancels in
// normalization; p <= ~e^6, fp16-safe). 8 waves each own 4 of 32 k-tiles ->
// no barriers in the matmul phase; one __syncthreads before the store phase.
// 2-stage register prefetch of K frags hides global-load latency.
// 66 KB LDS -> 2 blocks/CU so one block's compute overlaps the other's stores.
__global__ __launch_bounds__(512, 4) void scores_softmax(const _Float16* __restrict__ Qh,
                                                         float* __restrict__ out) {
    __shared__ __align__(16) _Float16 p[16][PSTRIDE];
    __shared__ float rsum_lds[8][16];

    // XCD-bijective swizzle (4096 % 8 == 0): each XCD gets 4 contiguous (b,h)
    // slices -> K working set ~1 MB per XCD L2.
    const int raw = blockIdx.x;
    const int bid = (raw & 7) * 512 + (raw >> 3);
    const int bh = bid >> 7;          // 0..31
    const int qb = bid & 127;         // 0..127
    const int b = bh >> 4, h = bh & 15;

    const int tid = threadIdx.x;
    const int w = tid >> 6;           // wave 0..7
    const int l = tid & 63;
    const int lq = l & 15, lg = l >> 4;
    const int q0 = qb * 16;
    const int hoff = h * 64;
    const _Float16* qbase = Qh + (size_t)b * SEQ * HIDDEN;

    // Q fragments (B operand): lane&15 = q-row, (lane>>4)*8 = d-offset
    const _Float16* qp = qbase + (size_t)(q0 + lq) * HIDDEN + hoff + lg * 8;
    const half8 aq0 = *(const half8*)qp;
    const half8 aq1 = *(const half8*)(qp + 32);

    // K fragment base (A operand): lane&15 = k-row within 16-tile
    const _Float16* kbase = qbase + (size_t)lq * HIDDEN + hoff + lg * 8;

    float rsum = 0.f;

    // 16 stages per wave: s = i*4 + n, k-tile = (w + 8*i)*64 + n*16
    half8 buf[3][2];
    {
        const _Float16* a0 = kbase + (size_t)(w * 64) * HIDDEN;        // s=0
        buf[0][0] = *(const half8*)a0;
        buf[0][1] = *(const half8*)(a0 + 32);
        const _Float16* a1 = kbase + (size_t)(w * 64 + 16) * HIDDEN;   // s=1
        buf[1][0] = *(const half8*)a1;
        buf[1][1] = *(const half8*)(a1 + 32);
    }
    #pragma unroll
    for (int s = 0; s < 16; ++s) {
        if (s + 2 < 16) {
            const int s2 = s + 2, i2 = s2 >> 2, n2 = s2 & 3;
            const _Float16* a = kbase + (size_t)((w + 8 * i2) * 64 + n2 * 16) * HIDDEN;
            buf[(s + 2) % 3][0] = *(const half8*)a;
            buf[(s + 2) % 3][1] = *(const half8*)(a + 32);
        }
        f32x4 acc = {};
        acc = __builtin_amdgcn_mfma_f32_16x16x32_f16(buf[s % 3][0], aq0, acc, 0, 0, 0);
        acc = __builtin_amdgcn_mfma_f32_16x16x32_f16(buf[s % 3][1], aq1, acc, 0, 0, 0);
        // C layout: col(q) = lane&15, row(k) = (lane>>4)*4 + reg
        const int i = s >> 2, n = s & 3;
        const int kb = (w + 8 * i) * 64 + n * 16 + lg * 4;
        float e0 = __expf(fmaf(acc[0], 0.125f, -8.0f));
        float e1 = __expf(fmaf(acc[1], 0.125f, -8.0f));
        float e2 = __expf(fmaf(acc[2], 0.125f, -8.0f));
        float e3 = __expf(fmaf(acc[3], 0.125f, -8.0f));
        rsum += (e0 + e1) + (e2 + e3);
        half4 hv;
        hv[0] = (_Float16)e0; hv[1] = (_Float16)e1;
        hv[2] = (_Float16)e2; hv[3] = (_Float16)e3;
        *(half4*)&p[lq][kb] = hv;
    }
    // fold the 4 lane-groups (each lane holds partial for q = lane&15)
    rsum += __shfl_xor(rsum, 16);
    rsum += __shfl_xor(rsum, 32);
    if (l < 16) rsum_lds[w][l] = rsum;
    __syncthreads();   // cheap: no global stores outstanding yet

    // ---- store phase: wave w -> rows w*2, w*2+1; 1 KB/instr coalesced nt stores ----
    const size_t outbase = (size_t)(b * 16 + h) * SEQ * SEQ;
    #pragma unroll
    for (int rr = 0; rr < 2; ++rr) {
        const int r = w * 2 + rr;
        const float rs = rsum_lds[0][r] + rsum_lds[1][r] + rsum_lds[2][r] + rsum_lds[3][r]
                       + rsum_lds[4][r] + rsum_lds[5][r] + rsum_lds[6][r] + rsum_lds[7][r];
        const float rinv = 1.0f / rs;
        float* orow = out + outbase + (size_t)(q0 + r) * SEQ;
        #pragma unroll
        for (int i = 0; i < 8; ++i) {
            half4 hv = *(const half4*)&p[r][i * 256 + l * 4];
            f32x4 v;
            v[0] = (float)hv[0] * rinv; v[1] = (float)hv[1] * rinv;
            v[2] = (float)hv[2] * rinv; v[3] = (float)hv[3] * rinv;
            __builtin_nontemporal_store(v, (f32x4*)(orow + i * 256 + l * 4));
        }
    }
}

extern "C" void kernel_launch(void* const* d_in, const int* in_sizes, int n_in,
                              void* d_out, int out_size, void* d_ws, size_t ws_size,
                              hipStream_t stream) {
    const float* x  = (const float*)d_in[0];   // [2,2048,1024]
    const float* Wq = (const float*)d_in[1];   // [1024,1024]
    const float* bq = (const float*)d_in[2];   // [1024]
    float* out = (float*)d_out;                // [2,16,2048,2048]

    _Float16* xh = (_Float16*)d_ws;                    // 8 MB
    _Float16* qh = xh + (size_t)4 * 1024 * 1024;       // 8 MB
    _Float16* wt = qh + (size_t)4 * 1024 * 1024;       // 2 MB

    const int nx = NB * SEQ * HIDDEN;  // 4194304
    cast_x<<<nx / (256 * 4), 256, 0, stream>>>(x, xh, nx);
    cast_wt<<<dim3(32, 32), dim3(32, 8), 0, stream>>>(Wq, wt);
    proj_gemm<<<dim3(NB * SEQ / 128, HIDDEN / 128), 256, 0, stream>>>(xh, wt, bq, qh);
    scores_softmax<<<NB * 16 * (SEQ / 16), 512, 0, stream>>>(qh, out);
}